// Round 1
// baseline (1871.148 us; speedup 1.0000x reference)
//
#include <hip/hip_runtime.h>
#include <math.h>

// ---- problem constants (from reference) ----
#define T_TOT  200000
#define EE     500
#define EI     100
#define SUBN   20
#define NCH    40      // 2*SUB
#define HIDN   20
#define BNO    34
#define TM     101     // basis kernel length
#define TNO    50      // history length / half kernel
#define HBNO   18
#define TT1    256     // t-tile for conv/relax/output kernels
#define EPSF   2e-5f   // sound margin for interval determinations

// ======================= setup: assignments, small kernels, basis ============
__global__ void k_setup(const float* __restrict__ Ce, const float* __restrict__ Ci,
                        const float* __restrict__ Wh, const float* __restrict__ Wspk,
                        const float* __restrict__ Tau,
                        int* __restrict__ ae, int* __restrict__ ai,
                        float* __restrict__ hkpos, float* __restrict__ hkneg,
                        float* __restrict__ spkk,
                        double* __restrict__ hkd, double* __restrict__ basisd)
{
    int tid = threadIdx.x;  // block 1024
    if (tid < EE) {
        int a = 0;
        for (int s = 0; s < SUBN; ++s) if (Ce[s * EE + tid] > 0.5f) a = s;
        ae[tid] = a;
    } else if (tid < EE + EI) {
        int e = tid - EE; int a = 0;
        for (int s = 0; s < SUBN; ++s) if (Ci[s * EI + e] > 0.5f) a = s;
        ai[e] = a;
    } else if (tid < 664) {
        // hk_r[j] = hist_kern[TNO - j], j in [1,TNO]; zero-fill rest of 64
        int j = tid - 600;
        double hk = 0.0;
        if (j >= 1 && j <= TNO) {
            int i = TNO - j;
            for (int b = 0; b < HBNO; ++b) {
                double d = (double)i - 3.0 * (double)b;
                hk += (double)Wh[b] * exp(-d * d / 3.0);
            }
        }
        hkd[j] = hk;
        hkpos[j] = (float)fmax(hk, 0.0);
        hkneg[j] = (float)fmin(hk, 0.0);
    } else if (tid < 728) {
        int m = tid - 664; float v = 0.f;
        if (m < TNO) {
            double tau2 = (double)Tau[0] * (double)Tau[0];
            double tt = (double)m / tau2;
            v = (float)(tt * exp(-tt) * (double)Wspk[0] * (double)Wspk[0]);
        }
        spkk[m] = v;
    }
    // Gaussian basis table (fp64), shared by kern1/kern4 construction
    for (int idx = tid; idx < BNO * TM; idx += blockDim.x) {
        int b = idx / TM, k = idx % TM;
        double d = (double)k - 3.0 * (double)b;
        basisd[idx] = exp(-d * d / 3.0);
    }
}

// ======================= build conv kernels from basis =======================
__global__ void k_makekern(const float* __restrict__ w1, const float* __restrict__ w4,
                           const double* __restrict__ basisd,
                           float* __restrict__ kern1, float* __restrict__ kern4)
{
    int idx = blockIdx.x * 256 + threadIdx.x;
    if (idx < HIDN * NCH * TM) {
        int h = idx % HIDN;
        int s = (idx / HIDN) % NCH;
        int k = idx / (HIDN * NCH);
        const float* wp = w1 + (h * NCH + s) * BNO;
        double acc = 0.0;
        for (int b = 0; b < BNO; ++b) acc += (double)wp[b] * basisd[b * TM + k];
        kern1[(k * NCH + s) * HIDN + h] = (float)acc;   // [k][s][h] layout
    } else {
        int j = idx - HIDN * NCH * TM;
        if (j < HIDN * TM) {
            int h = j % HIDN, k = j / HIDN;
            double acc = 0.0;
            for (int b = 0; b < BNO; ++b) acc += (double)w4[h * BNO + b] * basisd[b * TM + k];
            kern4[k * HIDN + h] = (float)acc;           // [k][h] layout
        }
    }
}

// ======================= synapse -> subunit routing ==========================
__global__ __launch_bounds__(256) void k_route(const float* __restrict__ Se,
                                               const float* __restrict__ Si,
                                               const int* __restrict__ ae,
                                               const int* __restrict__ ai,
                                               float* __restrict__ syn)
{
    __shared__ float acc[NCH * 64];
    __shared__ int sae[EE];
    __shared__ int sai[EI];
    int tid = threadIdx.x;
    for (int i = tid; i < NCH * 64; i += 256) acc[i] = 0.f;
    for (int i = tid; i < EE; i += 256) sae[i] = ae[i];
    for (int i = tid; i < EI; i += 256) sai[i] = ai[i];
    __syncthreads();
    int t0 = blockIdx.x * 64;              // T divisible by 64
    int lane = tid & 63, grp = tid >> 6;
    for (int ec = 0; ec < 8; ++ec) {
        int e = ec * 64 + lane;
        if (e < EE) {
            int a = sae[e];
            for (int ts = grp; ts < 64; ts += 4) {
                float v = Se[(size_t)(t0 + ts) * EE + e];   // coalesced across lanes
                if (v != 0.f) atomicAdd(&acc[a * 64 + ts], v);
            }
        }
    }
    for (int ec = 0; ec < 2; ++ec) {
        int e = ec * 64 + lane;
        if (e < EI) {
            int a = sai[e] + SUBN;
            for (int ts = grp; ts < 64; ts += 4) {
                float v = Si[(size_t)(t0 + ts) * EI + e];
                if (v != 0.f) atomicAdd(&acc[a * 64 + ts], v);
            }
        }
    }
    __syncthreads();
    for (int i = tid; i < NCH * 64; i += 256) {
        int s = i >> 6, ts = i & 63;
        syn[(size_t)s * T_TOT + t0 + ts] = acc[i];
    }
}

// ======================= conv1 (40ch -> 20ch, K=101) + leaky_relu ============
__global__ __launch_bounds__(256) void k_conv1(const float* __restrict__ syn,
                                               const float* __restrict__ kern1,
                                               float* __restrict__ out1)
{
    __shared__ float ssyn[NCH * (TT1 + 100)];   // 40*356*4 = 56,960 B
    int tid = threadIdx.x;
    int t0 = blockIdx.x * TT1;
    for (int i = tid; i < NCH * (TT1 + 100); i += 256) {
        int s = i / (TT1 + 100), x = i % (TT1 + 100);
        int g = t0 + x - TNO;
        ssyn[i] = (g >= 0 && g < T_TOT) ? syn[(size_t)s * T_TOT + g] : 0.f;
    }
    __syncthreads();
    int t = t0 + tid;
    if (t >= T_TOT) return;
    float a[HIDN];
#pragma unroll
    for (int h = 0; h < HIDN; ++h) a[h] = 0.f;
    for (int k = 0; k < TM; ++k) {
        const float* kp = kern1 + k * (NCH * HIDN);   // block-uniform -> s_load
        for (int s = 0; s < NCH; ++s) {
            float v = ssyn[s * (TT1 + 100) + tid + k];
            const float* kh = kp + s * HIDN;
#pragma unroll
            for (int h = 0; h < HIDN; ++h) a[h] = fmaf(v, kh[h], a[h]);
        }
    }
#pragma unroll
    for (int h = 0; h < HIDN; ++h) {
        float o = a[h];
        out1[(size_t)h * T_TOT + t] = (o > 0.f) ? o : 0.01f * o;
    }
}

// ======================= conv2 (fp64 acc) + logit threshold ==================
__global__ __launch_bounds__(256) void k_conv2(const float* __restrict__ out1,
                                               const float* __restrict__ kern4,
                                               const float* __restrict__ Theta,
                                               const float* __restrict__ u,
                                               double* __restrict__ xd,
                                               double* __restrict__ thrd,
                                               float* __restrict__ thr32)
{
    __shared__ float s1[HIDN * (TT1 + 100)];    // 28,480 B
    int tid = threadIdx.x;
    int t0 = blockIdx.x * TT1;
    for (int i = tid; i < HIDN * (TT1 + 100); i += 256) {
        int h = i / (TT1 + 100), x = i % (TT1 + 100);
        int g = t0 + x - TNO;
        s1[i] = (g >= 0 && g < T_TOT) ? out1[(size_t)h * T_TOT + g] : 0.f;
    }
    __syncthreads();
    int t = t0 + tid;
    if (t >= T_TOT) return;
    double acc = 0.0;
    for (int k = 0; k < TM; ++k) {
        const float* kp = kern4 + k * HIDN;
#pragma unroll
        for (int h = 0; h < HIDN; ++h)
            acc = fma((double)s1[h * (TT1 + 100) + tid + k], (double)kp[h], acc);
    }
    double x = acc + (double)Theta[0];
    double uu = (double)u[t];
    // spike  <=>  u < sigmoid(x + a)  <=>  a > logit(u) - x
    double th = (log(uu) - log1p(-uu)) - x;     // u==0 -> -inf -> always spike (correct)
    xd[t] = x; thrd[t] = th; thr32[t] = (float)th;
}

// ======================= interval state init ================================
__global__ void k_init(float* __restrict__ blo, float* __restrict__ bhi,
                       int* __restrict__ dirty)
{
    int i = blockIdx.x * 256 + threadIdx.x;
    if (i < T_TOT + 64) {
        blo[i] = 0.f;                                        // index = t + TNO
        bhi[i] = (i >= TNO && i < T_TOT + TNO) ? 1.f : 0.f;  // unknown = (0,1)
    }
    if (i < 256) dirty[i] = 0;
}

// ======================= sound interval relaxation round =====================
__global__ __launch_bounds__(256) void k_relax(const float* __restrict__ thr32,
                                               const float* __restrict__ hkpos,
                                               const float* __restrict__ hkneg,
                                               float* __restrict__ blo,
                                               float* __restrict__ bhi)
{
    __shared__ float slo[TT1 + 64], shi[TT1 + 64], shp[64], shn[64];
    int tid = threadIdx.x;
    int t0 = blockIdx.x * TT1;
    for (int i = tid; i < TT1 + TNO; i += 256) {
        int g = t0 + i;                         // covers times t0-TNO .. t0+TT1-1
        bool ok = g < T_TOT + 64;
        slo[i] = ok ? blo[g] : 0.f;
        shi[i] = ok ? bhi[g] : 0.f;
    }
    if (tid < 64) { shp[tid] = hkpos[tid]; shn[tid] = hkneg[tid]; }
    __syncthreads();
    int t = t0 + tid;
    if (t >= T_TOT) return;
    float ml = slo[tid + TNO], mh = shi[tid + TNO];
    if (ml == mh) return;                        // already determined
    float lo = 0.f, hi = 0.f;
    for (int j = 1; j <= TNO; ++j) {
        float bl = slo[tid + TNO - j], bh = shi[tid + TNO - j];
        float hp = shp[j], hn = shn[j];
        lo = fmaf(hp, bl, lo); lo = fmaf(hn, bh, lo);
        hi = fmaf(hp, bh, hi); hi = fmaf(hn, bl, hi);
    }
    float th = thr32[t];
    if (lo > th + EPSF)      { blo[t + TNO] = 1.f; bhi[t + TNO] = 1.f; }
    else if (hi < th - EPSF) { blo[t + TNO] = 0.f; bhi[t + TNO] = 0.f; }
}

// ======================= per-tile dirty counts ===============================
__global__ __launch_bounds__(1024) void k_mark(const float* __restrict__ blo,
                                               const float* __restrict__ bhi,
                                               int* __restrict__ dirty)
{
    int t = blockIdx.x * 1024 + threadIdx.x;
    int unk = (t < T_TOT) && (blo[t + TNO] != bhi[t + TNO]);
    int c = __syncthreads_count(unk);
    if (threadIdx.x == 0) dirty[blockIdx.x] = c;
}

// ======================= exact sequential cleanup (guarantee) ================
__global__ __launch_bounds__(1024) void k_cleanup(const double* __restrict__ thrd,
                                                  const double* __restrict__ hkd,
                                                  const int* __restrict__ dirty,
                                                  float* __restrict__ blo,
                                                  float* __restrict__ bhi)
{
    __shared__ float sb[64 + 1024];
    __shared__ double shk[64];
    __shared__ int sflag;
    int tid = threadIdx.x;
    if (tid < 64) shk[tid] = (tid >= 1 && tid <= TNO) ? hkd[tid] : 0.0;
    const int NT = (T_TOT + 1023) / 1024;
    for (int tile = 0; tile < NT; ++tile) {
        if (tid == 0) sflag = dirty[tile];
        __syncthreads();
        int cnt = sflag;
        __syncthreads();
        if (cnt == 0) continue;                  // uniform branch
        if (tid < 64) {
            int tp = tile * 1024 - 64 + tid;     // tail bits (already final)
            sb[tid] = (tp >= 0) ? blo[tp + TNO] : 0.f;
        }
        int t = tile * 1024 + tid;
        float v = 0.f;
        if (t < T_TOT) {
            float l = blo[t + TNO], h = bhi[t + TNO];
            v = (l == h) ? l : -1.f;             // -1 marks unknown
        }
        sb[64 + tid] = v;
        __syncthreads();
        if (tid == 0) {
            for (int i = 0; i < 1024; ++i) {
                if (sb[64 + i] < 0.f) {
                    double a = 0.0;
                    for (int j = 1; j <= TNO; ++j) a += shk[j] * (double)sb[64 + i - j];
                    int tt = tile * 1024 + i;
                    float s = (a > thrd[tt]) ? 1.f : 0.f;
                    sb[64 + i] = s; blo[tt + TNO] = s; bhi[tt + TNO] = s;
                }
            }
            __threadfence_block();
        }
        __syncthreads();
    }
}

// ======================= outputs: spk_filt + prob_out ========================
__global__ __launch_bounds__(256) void k_out(const float* __restrict__ blo,
                                             const float* __restrict__ spkk,
                                             const double* __restrict__ hkd,
                                             const double* __restrict__ xd,
                                             float* __restrict__ outp)
{
    __shared__ float sb[TT1 + 64];
    __shared__ float ssp[64];
    __shared__ double shk[64];
    int tid = threadIdx.x;
    int t0 = blockIdx.x * TT1;
    for (int i = tid; i < TT1 + TNO; i += 256) {
        int g = t0 + i;
        sb[i] = (g < T_TOT + 64) ? blo[g] : 0.f;
    }
    if (tid < 64) { ssp[tid] = spkk[tid]; shk[tid] = hkd[tid]; }
    __syncthreads();
    int t = t0 + tid;
    if (t >= T_TOT) return;
    float filt = 0.f;
    double a = 0.0;
    for (int m = 1; m <= TNO; ++m) {
        float b = sb[tid + TNO - m];             // spk[t-m]
        filt = fmaf(b, ssp[m - 1], filt);        // spk_kern[m-1]
        a += shk[m] * (double)b;                 // hist feedback (exact)
    }
    double p = 1.0 / (1.0 + exp(-(xd[t] + a)));
    outp[t] = filt;
    outp[T_TOT + t] = (float)p;
}

// ======================= launcher ===========================================
extern "C" void kernel_launch(void* const* d_in, const int* in_sizes, int n_in,
                              void* d_out, int out_size, void* d_ws, size_t ws_size,
                              hipStream_t stream)
{
    (void)in_sizes; (void)n_in; (void)out_size; (void)ws_size;
    const float* Se = (const float*)d_in[0];
    const float* Si = (const float*)d_in[1];
    const float* Ce = (const float*)d_in[2];
    const float* Ci = (const float*)d_in[3];
    const float* w1 = (const float*)d_in[4];
    const float* w4 = (const float*)d_in[5];
    const float* Wh = (const float*)d_in[6];
    const float* Th = (const float*)d_in[7];
    const float* Ws = (const float*)d_in[8];
    const float* Ta = (const float*)d_in[9];
    const float* u  = (const float*)d_in[10];

    char* w = (char*)d_ws;
    size_t off = 0;
    auto alloc = [&](size_t n) { size_t o = off; off += (n + 15) & ~(size_t)15; return o; };
    float*  kern1  = (float*)(w + alloc((size_t)TM * NCH * HIDN * 4));
    float*  kern4  = (float*)(w + alloc((size_t)TM * HIDN * 4));
    double* basisd = (double*)(w + alloc((size_t)BNO * TM * 8));
    int*    ae     = (int*)(w + alloc(EE * 4));
    int*    ai     = (int*)(w + alloc(EI * 4));
    float*  hkpos  = (float*)(w + alloc(64 * 4));
    float*  hkneg  = (float*)(w + alloc(64 * 4));
    float*  spkk   = (float*)(w + alloc(64 * 4));
    double* hkd    = (double*)(w + alloc(64 * 8));
    double* xd     = (double*)(w + alloc((size_t)T_TOT * 8));
    double* thrd   = (double*)(w + alloc((size_t)T_TOT * 8));
    float*  thr32  = (float*)(w + alloc((size_t)T_TOT * 4));
    float*  blo    = (float*)(w + alloc((size_t)(T_TOT + 64) * 4));
    float*  bhi    = (float*)(w + alloc((size_t)(T_TOT + 64) * 4));
    int*    dirty  = (int*)(w + alloc(256 * 4));
    float*  syn    = (float*)(w + alloc((size_t)NCH * T_TOT * 4));
    float*  out1   = (float*)(w + alloc((size_t)HIDN * T_TOT * 4));
    // total ws use ~54 MB

    k_setup<<<1, 1024, 0, stream>>>(Ce, Ci, Wh, Ws, Ta, ae, ai, hkpos, hkneg, spkk, hkd, basisd);
    k_makekern<<<(HIDN * NCH * TM + HIDN * TM + 255) / 256, 256, 0, stream>>>(w1, w4, basisd, kern1, kern4);
    k_route<<<T_TOT / 64, 256, 0, stream>>>(Se, Si, ae, ai, syn);
    k_conv1<<<(T_TOT + TT1 - 1) / TT1, 256, 0, stream>>>(syn, kern1, out1);
    k_conv2<<<(T_TOT + TT1 - 1) / TT1, 256, 0, stream>>>(out1, kern4, Th, u, xd, thrd, thr32);
    k_init<<<(T_TOT + 64 + 255) / 256, 256, 0, stream>>>(blo, bhi, dirty);
    for (int r = 0; r < 12; ++r)
        k_relax<<<(T_TOT + TT1 - 1) / TT1, 256, 0, stream>>>(thr32, hkpos, hkneg, blo, bhi);
    k_mark<<<(T_TOT + 1023) / 1024, 1024, 0, stream>>>(blo, bhi, dirty);
    k_cleanup<<<1, 1024, 0, stream>>>(thrd, hkd, dirty, blo, bhi);
    k_out<<<(T_TOT + TT1 - 1) / TT1, 256, 0, stream>>>(blo, spkk, hkd, xd, (float*)d_out);
}